// Round 5
// baseline (857.045 us; speedup 1.0000x reference)
//
#include <hip/hip_runtime.h>
#include <hip/hip_bf16.h>
#include <cstdint>
#include <cstddef>

typedef unsigned short u16;
typedef __attribute__((ext_vector_type(8))) __bf16 bf16x8;
typedef __attribute__((ext_vector_type(4))) float f32x4;
typedef __attribute__((ext_vector_type(8))) unsigned short us8;

#define NDM 768
#define NDI 3072
#define NTT 1024
#define NBB 16
#define NM (NBB*NTT)   // 16384 rows total

// ---------- helpers ----------
__device__ __forceinline__ u16 f2bf(float f) {
  unsigned u = __builtin_bit_cast(unsigned, f);
  u += 0x7fffu + ((u >> 16) & 1u);          // RNE
  return (u16)(u >> 16);
}
__device__ __forceinline__ float bf2f(u16 b) {
  return __builtin_bit_cast(float, ((unsigned)b) << 16);
}
__device__ __forceinline__ float silu_f(float v) {
  return v * (1.0f / (1.0f + __expf(-v)));
}
__device__ __forceinline__ void gload16(const u16* g, u16* l) {
  __builtin_amdgcn_global_load_lds((const __attribute__((address_space(1))) void*)g,
                                   (__attribute__((address_space(3))) void*)l, 16, 0, 0);
}

// ---------- fp32 -> bf16 convert ----------
__global__ __launch_bounds__(256)
void k_f32_to_bf16(const float* __restrict__ in, u16* __restrict__ out, int n4) {
  const int i = blockIdx.x * 256 + threadIdx.x;
  if (i < n4) {
    float4 v = ((const float4*)in)[i];
    ushort4 o;
    o.x = f2bf(v.x); o.y = f2bf(v.y); o.z = f2bf(v.z); o.w = f2bf(v.w);
    ((ushort4*)out)[i] = o;
  }
}

// conv_w [E][3][3] -> wTb [9][E] (bf16)
__global__ __launch_bounds__(256)
void k_convw_t(const float* __restrict__ cw, u16* __restrict__ wTb) {
  const int e = blockIdx.x * 256 + threadIdx.x;
  if (e < NDI) {
#pragma unroll
    for (int t = 0; t < 9; t++) wTb[t * NDI + e] = f2bf(cw[e * 9 + t]);
  }
}

// ---------- RMSNorm: x[M,768] f32 -> h[M,768] bf16 ----------
__global__ __launch_bounds__(256)
void k_rmsnorm(const float* __restrict__ x, const float* __restrict__ w, u16* __restrict__ h) {
  const int row  = blockIdx.x * 4 + (threadIdx.x >> 6);
  const int lane = threadIdx.x & 63;
  const float4* xr = (const float4*)(x + (size_t)row * NDM);
  float4 a = xr[lane], b = xr[lane + 64], c = xr[lane + 128];
  float ss = a.x*a.x + a.y*a.y + a.z*a.z + a.w*a.w
           + b.x*b.x + b.y*b.y + b.z*b.z + b.w*b.w
           + c.x*c.x + c.y*c.y + c.z*c.z + c.w*c.w;
#pragma unroll
  for (int off = 32; off > 0; off >>= 1) ss += __shfl_xor(ss, off);
  const float r = rsqrtf(ss * (1.0f / NDM) + 1e-5f);
  const float4* wr = (const float4*)w;
  float4 wa = wr[lane], wb = wr[lane + 64], wc = wr[lane + 128];
  ushort4 oa, ob, oc;
  oa.x = f2bf(a.x * r * wa.x); oa.y = f2bf(a.y * r * wa.y);
  oa.z = f2bf(a.z * r * wa.z); oa.w = f2bf(a.w * r * wa.w);
  ob.x = f2bf(b.x * r * wb.x); ob.y = f2bf(b.y * r * wb.y);
  ob.z = f2bf(b.z * r * wb.z); ob.w = f2bf(b.w * r * wb.w);
  oc.x = f2bf(c.x * r * wc.x); oc.y = f2bf(c.y * r * wc.y);
  oc.z = f2bf(c.z * r * wc.z); oc.w = f2bf(c.w * r * wc.w);
  ushort4* hr = (ushort4*)(h + (size_t)row * NDM);
  hr[lane] = oa; hr[lane + 64] = ob; hr[lane + 128] = oc;
}

// ---------- NT GEMM, 128x128 tile, BK=32, 4 waves (m97 structure), 1D grid + XCD swizzle ----------
// T2 staging swizzle: LDS dest of global_load_lds is linear (rule 21), so the bank-conflict fix
// is applied as an involution on the GLOBAL source k-slot + the matching XOR on the LDS read
// address. Per-thread constant xko -> zero in-loop VALU cost.
// C[m,n] = sum_k A[m,k]*B[n,k].
// MODE 0: bf16 store -> C0 (stride N)
// MODE 2: bf16 store scaled by expf(*scalep)/1024 -> C0
// MODE 3: f32 store  -> C0 = X + bf16(C1) + acc   (stride N)
// MODE 5: split cols: col<3072 -> C0 bf16 nt-store; col>=3072 -> C1 silu bf16 nt-store
template <int MODE>
__global__ __launch_bounds__(256)
void k_gemm_nt(const u16* __restrict__ A, const u16* __restrict__ B,
               void* __restrict__ C0, void* __restrict__ C1,
               const float* __restrict__ X, const float* __restrict__ scalep,
               int N, int Kd, int nTiles,
               long sAb, long sBb, long sCb, int mPerBatchB, long sBm) {
  __shared__ u16 As[128 * 32];
  __shared__ u16 Bs[128 * 32];
  const int bz = blockIdx.z;
  A += (size_t)bz * sAb;
  B += (size_t)bz * sBb;

  // XCD-aware bijective swizzle (identity when nwg % 8 != 0)
  const int nwg = gridDim.x;
  const int id = blockIdx.x;
  const int sid = ((nwg & 7) == 0) ? ((id & 7) * (nwg >> 3) + (id >> 3)) : id;
  const int mt = sid / nTiles, nt = sid - mt * nTiles;
  const int m0 = mt * 128, n0 = nt * 128;
  if (mPerBatchB > 0) B += (size_t)(m0 / mPerBatchB) * sBm;

  const int lane = threadIdx.x & 63, wid = threadIdx.x >> 6;
  const int wm = wid >> 1, wn = wid & 1;

  f32x4 zero = {0.f, 0.f, 0.f, 0.f};
  f32x4 acc[4][4];
#pragma unroll
  for (int m = 0; m < 4; m++)
#pragma unroll
    for (int n = 0; n < 4; n++) acc[m][n] = zero;

  // T2: global source k-slot pre-swizzle (involution with the LDS read XOR below)
  const int kslot = ((lane & 3) ^ ((lane >> 3) & 3)) * 8;
  const u16* Ag = A + (size_t)(m0 + wid * 32 + (lane >> 2)) * Kd + kslot;
  const u16* Bg = B + (size_t)(n0 + wid * 32 + (lane >> 2)) * Kd + kslot;
  u16* AsW = &As[(wid * 32) * 32];
  u16* BsW = &Bs[(wid * 32) * 32];
  const int rowSkip = 16 * Kd;
  const int fr = lane & 15;
  // logical k-offset (lane>>4)*8, XORed with the row-dependent slot swizzle
  // ((row>>1)&3) == ((fr>>1)&3) for every fragment row this thread touches
  const int xko = (((lane >> 4) ^ ((fr >> 1) & 3)) << 3);

  for (int kt = 0; kt < Kd; kt += 32) {
    gload16(Ag, AsW);
    gload16(Ag + rowSkip, AsW + 16 * 32);
    gload16(Bg, BsW);
    gload16(Bg + rowSkip, BsW + 16 * 32);
    Ag += 32; Bg += 32;
    __syncthreads();
    bf16x8 af[4], bfr[4];
#pragma unroll
    for (int m = 0; m < 4; m++)
      af[m] = *(const bf16x8*)&As[(wm * 64 + m * 16 + fr) * 32 + xko];
#pragma unroll
    for (int n = 0; n < 4; n++)
      bfr[n] = *(const bf16x8*)&Bs[(wn * 64 + n * 16 + fr) * 32 + xko];
#pragma unroll
    for (int m = 0; m < 4; m++)
#pragma unroll
      for (int n = 0; n < 4; n++)
        acc[m][n] = __builtin_amdgcn_mfma_f32_16x16x32_bf16(af[m], bfr[n], acc[m][n], 0, 0, 0);
    __syncthreads();
  }

  float sc = 1.0f;
  if (MODE == 2) sc = __expf(scalep[0]) * (1.0f / 1024.0f);
  const size_t cb = (size_t)bz * sCb;
#pragma unroll
  for (int m = 0; m < 4; m++) {
#pragma unroll
    for (int n = 0; n < 4; n++) {
      const int col = n0 + wn * 64 + n * 16 + (lane & 15);
      const int rb  = m0 + wm * 64 + m * 16 + ((lane >> 4) << 2);
#pragma unroll
      for (int q = 0; q < 4; q++) {
        const float v = acc[m][n][q];
        if (MODE == 0) {
          ((u16*)C0)[cb + (size_t)(rb + q) * N + col] = f2bf(v);
        } else if (MODE == 2) {
          ((u16*)C0)[cb + (size_t)(rb + q) * N + col] = f2bf(v * sc);
        } else if (MODE == 3) {
          const size_t idx = (size_t)(rb + q) * N + col;
          ((float*)C0)[idx] = X[idx] + bf2f(((const u16*)C1)[idx]) + v;
        } else { // MODE 5: streaming nt stores (write-allocate avoidance; not L3-served anyway)
          if (n0 < 3072)
            __builtin_nontemporal_store(f2bf(v), &((u16*)C0)[(size_t)(rb + q) * 3072 + col]);
          else
            __builtin_nontemporal_store(f2bf(silu_f(v)),
                                        &((u16*)C1)[(size_t)(rb + q) * 3072 + (col - 3072)]);
        }
      }
    }
  }
}

// ---------- depthwise 3x3 conv + bias + silu, * pre-silu'd gate, in-place into gate ----------
// val: [M, E] bf16 (t = i*32+j spatial), gate holds silu(gate_pre) on input, gated on output
__global__ __launch_bounds__(384)
void k_conv_gate(const u16* __restrict__ val, u16* __restrict__ gate,
                 const u16* __restrict__ wTb, const float* __restrict__ bias) {
  const int tid = threadIdx.x;
  const int m = blockIdx.x * 2 + (tid >= 192);   // wave-uniform (192 = 3 waves)
  const int e0 = (tid % 192) * 16;
  const int j = m & 31, i = (m >> 5) & 31;
  float acc[16];
  {
    const float4* bp = (const float4*)(bias + e0);
    float4 b0 = bp[0], b1 = bp[1], b2 = bp[2], b3 = bp[3];
    acc[0]=b0.x; acc[1]=b0.y; acc[2]=b0.z; acc[3]=b0.w;
    acc[4]=b1.x; acc[5]=b1.y; acc[6]=b1.z; acc[7]=b1.w;
    acc[8]=b2.x; acc[9]=b2.y; acc[10]=b2.z; acc[11]=b2.w;
    acc[12]=b3.x; acc[13]=b3.y; acc[14]=b3.z; acc[15]=b3.w;
  }
  const u16* vb = val + (size_t)m * NDI + e0;
#pragma unroll
  for (int di = -1; di <= 1; di++) {
    if ((unsigned)(i + di) >= 32u) continue;
#pragma unroll
    for (int dj = -1; dj <= 1; dj++) {
      if ((unsigned)(j + dj) >= 32u) continue;
      const u16* vp = vb + (ptrdiff_t)(di * 32 + dj) * NDI;
      us8 v0 = *(const us8*)vp, v1 = *(const us8*)(vp + 8);
      const u16* wp = wTb + ((di + 1) * 3 + (dj + 1)) * NDI + e0;
      us8 w0 = *(const us8*)wp, w1 = *(const us8*)(wp + 8);
#pragma unroll
      for (int q = 0; q < 8; q++) acc[q]     += bf2f(v0[q]) * bf2f(w0[q]);
#pragma unroll
      for (int q = 0; q < 8; q++) acc[8 + q] += bf2f(v1[q]) * bf2f(w1[q]);
    }
  }
  u16* gp = gate + (size_t)m * NDI + e0;
  us8 g0 = *(const us8*)gp, g1 = *(const us8*)(gp + 8);
  us8 o0, o1;
#pragma unroll
  for (int q = 0; q < 8; q++) o0[q] = f2bf(silu_f(acc[q]) * bf2f(g0[q]));
#pragma unroll
  for (int q = 0; q < 8; q++) o1[q] = f2bf(silu_f(acc[8 + q]) * bf2f(g1[q]));
  *(us8*)gp = o0;
  *(us8*)(gp + 8) = o1;
}

// ---------- bf16 transpose: in [NB][NT][NDM] -> out [NB][NDM][NT] ----------
__global__ __launch_bounds__(256)
void k_transpose(const u16* __restrict__ in, u16* __restrict__ out) {
  __shared__ u16 tile[64][65];
  const int d0 = blockIdx.x * 64, t0 = blockIdx.y * 64, b = blockIdx.z;
  const int lx = threadIdx.x & 15, ly = threadIdx.x >> 4;
  const u16* ip = in + ((size_t)b * NTT + t0) * NDM + d0;
#pragma unroll
  for (int p = 0; p < 4; p++) {
    const int r = ly + p * 16;
    ushort4 v = *(const ushort4*)(ip + (size_t)r * NDM + lx * 4);
    tile[r][lx * 4 + 0] = v.x; tile[r][lx * 4 + 1] = v.y;
    tile[r][lx * 4 + 2] = v.z; tile[r][lx * 4 + 3] = v.w;
  }
  __syncthreads();
  u16* op = out + ((size_t)b * NDM + d0) * NTT + t0;
#pragma unroll
  for (int p = 0; p < 4; p++) {
    const int r = ly + p * 16;
    ushort4 v;
    v.x = tile[lx * 4 + 0][r]; v.y = tile[lx * 4 + 1][r];
    v.z = tile[lx * 4 + 2][r]; v.w = tile[lx * 4 + 3][r];
    *(ushort4*)(op + (size_t)r * NTT + lx * 4) = v;
  }
}

// ---------- launch ----------
extern "C" void kernel_launch(void* const* d_in, const int* in_sizes, int n_in,
                              void* d_out, int out_size, void* d_ws, size_t ws_size,
                              hipStream_t stream) {
  const float* x      = (const float*)d_in[0];
  const float* norm_w = (const float*)d_in[1];
  const float* w_proj = (const float*)d_in[2];
  const float* w_gate = (const float*)d_in[3];
  const float* conv_w = (const float*)d_in[4];
  const float* conv_b = (const float*)d_in[5];
  const float* w_out  = (const float*)d_in[6];
  const float* w_k    = (const float*)d_in[7];
  const float* w_v    = (const float*)d_in[8];
  const float* lalpha = (const float*)d_in[9];

  // d_out as scratch for h + bf16 weights (all dead before final GEMM writes d_out)
  char* ob = (char*)d_out;
  u16* h    = (u16*)(ob);                    // 25,165,824 B
  u16* wcat = (u16*)(ob + 25165824);         //  9,437,184  [w_proj ; w_gate] (6144 x 768)
  u16* wob  = (u16*)(ob + 34603008);         //  4,718,592
  u16* wkb  = (u16*)(ob + 39321600);         //  1,179,648
  u16* wvb  = (u16*)(ob + 40501248);         //  1,179,648
  u16* wTb  = (u16*)(ob + 41680896);         //     55,296  (total 41.7MB < 50.3MB)

  char* ws = (char*)d_ws;
  u16* valp  = (u16*)(ws);                   // 100,663,296  [dead after conv]
  u16* gateb = (u16*)(ws + 100663296);       // 100,663,296  silu(gate)->gated [dead after out GEMM]
  u16* outb  = (u16*)(ws);                   //  25,165,824  (valp region, valp dead)
  u16* Kbf   = (u16*)(ws + 25165824);        //  25,165,824
  u16* Vbf   = (u16*)(ws + 50331648);        //  25,165,824
  u16* Kt    = (u16*)(ws + 100663296);       //  25,165,824  (gateb region, gateb dead)
  u16* Vt    = (u16*)(ws + 125829120);       //  25,165,824
  u16* Wt    = (u16*)(ws + 150994944);       //  18,874,368  (max used 169.9MB)

  // weight preprocessing
  k_f32_to_bf16<<<2304, 256, 0, stream>>>(w_proj, wcat,           589824);
  k_f32_to_bf16<<<2304, 256, 0, stream>>>(w_gate, wcat + 2359296, 589824);
  k_f32_to_bf16<<<2304, 256, 0, stream>>>(w_out,  wob, 589824);
  k_f32_to_bf16<<<576,  256, 0, stream>>>(w_k,    wkb, 147456);
  k_f32_to_bf16<<<576,  256, 0, stream>>>(w_v,    wvb, 147456);
  k_convw_t<<<12, 256, 0, stream>>>(conv_w, wTb);

  // h = rmsnorm(x) in bf16
  k_rmsnorm<<<4096, 256, 0, stream>>>(x, norm_w, h);

  // [val_pre | silu(gate_pre)] = h @ [w_proj;w_gate]^T   [16384 x 6144]
  k_gemm_nt<5><<<6144, 256, 0, stream>>>(h, wcat, valp, gateb, nullptr, nullptr,
                                         6144, NDM, 48, 0, 0, 0, 0, 0);
  // gated = silu(conv(val_pre)+b) * siluGate   (in-place into gateb)
  k_conv_gate<<<8192, 384, 0, stream>>>(valp, gateb, wTb, conv_b);

  // out = gated @ w_out^T -> bf16   [16384 x 768]
  k_gemm_nt<0><<<768, 256, 0, stream>>>(gateb, wob, outb, nullptr, nullptr, nullptr,
                                        NDM, NDI, 6, 0, 0, 0, 0, 0);
  // K = h @ w_k^T ; V = out @ w_v^T
  k_gemm_nt<0><<<768, 256, 0, stream>>>(h, wkb, Kbf, nullptr, nullptr, nullptr,
                                        NDM, NDM, 6, 0, 0, 0, 0, 0);
  k_gemm_nt<0><<<768, 256, 0, stream>>>(outb, wvb, Vbf, nullptr, nullptr, nullptr,
                                        NDM, NDM, 6, 0, 0, 0, 0, 0);
  // K^T, V^T per batch: [B, D, T]
  k_transpose<<<dim3(12, 16, 16), 256, 0, stream>>>(Kbf, Kt);
  k_transpose<<<dim3(12, 16, 16), 256, 0, stream>>>(Vbf, Vt);

  // Wt[b][e][d] = (alpha/T) * sum_t V[t,e] K[t,d]
  k_gemm_nt<2><<<dim3(36, 1, 16), 256, 0, stream>>>(Vt, Kt, Wt, nullptr, nullptr, lalpha,
                                                    NDM, NTT, 6,
                                                    (long)NDM * NTT, (long)NDM * NTT,
                                                    (long)NDM * NDM, 0, 0);
  // final: d_out = x + out + sum_d K[t,d] * Wt[e,d]
  k_gemm_nt<3><<<768, 256, 0, stream>>>(Kbf, Wt, d_out, outb, x, nullptr,
                                        NDM, NDM, 6, 0, 0, 0,
                                        NTT, (long)NDM * NDM);
}

// Round 7
// 753.539 us; speedup vs baseline: 1.1374x; 1.1374x over previous
//
#include <hip/hip_runtime.h>
#include <hip/hip_bf16.h>
#include <cstdint>
#include <cstddef>

typedef unsigned short u16;
typedef __attribute__((ext_vector_type(8))) __bf16 bf16x8;
typedef __attribute__((ext_vector_type(4))) float f32x4;
typedef __attribute__((ext_vector_type(8))) unsigned short us8;

#define NDM 768
#define NDI 3072
#define NTT 1024
#define NBB 16
#define NM (NBB*NTT)   // 16384 rows total

// ---------- helpers ----------
__device__ __forceinline__ u16 f2bf(float f) {
  unsigned u = __builtin_bit_cast(unsigned, f);
  u += 0x7fffu + ((u >> 16) & 1u);          // RNE
  return (u16)(u >> 16);
}
__device__ __forceinline__ float bf2f(u16 b) {
  return __builtin_bit_cast(float, ((unsigned)b) << 16);
}
__device__ __forceinline__ float silu_f(float v) {
  return v * (1.0f / (1.0f + __expf(-v)));
}
__device__ __forceinline__ void gload16(const u16* g, u16* l) {
  __builtin_amdgcn_global_load_lds((const __attribute__((address_space(1))) void*)g,
                                   (__attribute__((address_space(3))) void*)l, 16, 0, 0);
}

// ---------- fp32 -> bf16 convert ----------
__global__ __launch_bounds__(256)
void k_f32_to_bf16(const float* __restrict__ in, u16* __restrict__ out, int n4) {
  const int i = blockIdx.x * 256 + threadIdx.x;
  if (i < n4) {
    float4 v = ((const float4*)in)[i];
    ushort4 o;
    o.x = f2bf(v.x); o.y = f2bf(v.y); o.z = f2bf(v.z); o.w = f2bf(v.w);
    ((ushort4*)out)[i] = o;
  }
}

// conv_w [E][3][3] -> wTb [9][E] (bf16)
__global__ __launch_bounds__(256)
void k_convw_t(const float* __restrict__ cw, u16* __restrict__ wTb) {
  const int e = blockIdx.x * 256 + threadIdx.x;
  if (e < NDI) {
#pragma unroll
    for (int t = 0; t < 9; t++) wTb[t * NDI + e] = f2bf(cw[e * 9 + t]);
  }
}

// ---------- RMSNorm: x[M,768] f32 -> h[M,768] bf16 ----------
__global__ __launch_bounds__(256)
void k_rmsnorm(const float* __restrict__ x, const float* __restrict__ w, u16* __restrict__ h) {
  const int row  = blockIdx.x * 4 + (threadIdx.x >> 6);
  const int lane = threadIdx.x & 63;
  const float4* xr = (const float4*)(x + (size_t)row * NDM);
  float4 a = xr[lane], b = xr[lane + 64], c = xr[lane + 128];
  float ss = a.x*a.x + a.y*a.y + a.z*a.z + a.w*a.w
           + b.x*b.x + b.y*b.y + b.z*b.z + b.w*b.w
           + c.x*c.x + c.y*c.y + c.z*c.z + c.w*c.w;
#pragma unroll
  for (int off = 32; off > 0; off >>= 1) ss += __shfl_xor(ss, off);
  const float r = rsqrtf(ss * (1.0f / NDM) + 1e-5f);
  const float4* wr = (const float4*)w;
  float4 wa = wr[lane], wb = wr[lane + 64], wc = wr[lane + 128];
  ushort4 oa, ob, oc;
  oa.x = f2bf(a.x * r * wa.x); oa.y = f2bf(a.y * r * wa.y);
  oa.z = f2bf(a.z * r * wa.z); oa.w = f2bf(a.w * r * wa.w);
  ob.x = f2bf(b.x * r * wb.x); ob.y = f2bf(b.y * r * wb.y);
  ob.z = f2bf(b.z * r * wb.z); ob.w = f2bf(b.w * r * wb.w);
  oc.x = f2bf(c.x * r * wc.x); oc.y = f2bf(c.y * r * wc.y);
  oc.z = f2bf(c.z * r * wc.z); oc.w = f2bf(c.w * r * wc.w);
  ushort4* hr = (ushort4*)(h + (size_t)row * NDM);
  hr[lane] = oa; hr[lane + 64] = ob; hr[lane + 128] = oc;
}

// ---------- NT GEMM, 128x128 tile, BK=32, 4 waves (m97 structure), 1D grid + XCD swizzle ----------
// T2 staging swizzle: LDS dest of global_load_lds is linear (rule 21); bank-conflict fix is an
// involution on the GLOBAL source k-slot + matching XOR on the LDS read address (per-thread const).
// Epilogue (MODE 0/2/5): stage C-tile in LDS, then full-line us8 coalesced stores
// (kills L2 write-allocate fetch from half-line bf16 stores; 64 -> 8 stores/thread).
// C[m,n] = sum_k A[m,k]*B[n,k].
// MODE 0: bf16 store -> C0 (stride N)
// MODE 2: bf16 store scaled by expf(*scalep)/1024 -> C0
// MODE 3: f32 store  -> C0 = X + bf16(C1) + acc   (stride N, direct — already full-line)
// MODE 5: split cols: col<3072 -> C0 bf16 (stride 3072); col>=3072 -> C1 silu bf16 (stride 3072)
template <int MODE>
__global__ __launch_bounds__(256)
void k_gemm_nt(const u16* __restrict__ A, const u16* __restrict__ B,
               void* __restrict__ C0, void* __restrict__ C1,
               const float* __restrict__ X, const float* __restrict__ scalep,
               int N, int Kd, int nTiles,
               long sAb, long sBb, long sCb, int mPerBatchB, long sBm) {
  __shared__ u16 smem[128 * 136];            // K-loop: As=smem[0..4095], Bs=smem[4096..8191]
  u16* As = smem;                            // epilogue: full 128x136 bf16 C-tile
  u16* Bs = smem + 4096;
  const int bz = blockIdx.z;
  A += (size_t)bz * sAb;
  B += (size_t)bz * sBb;

  // XCD-aware bijective swizzle (identity when nwg % 8 != 0)
  const int nwg = gridDim.x;
  const int id = blockIdx.x;
  const int sid = ((nwg & 7) == 0) ? ((id & 7) * (nwg >> 3) + (id >> 3)) : id;
  const int mt = sid / nTiles, nt = sid - mt * nTiles;
  const int m0 = mt * 128, n0 = nt * 128;
  if (mPerBatchB > 0) B += (size_t)(m0 / mPerBatchB) * sBm;

  const int lane = threadIdx.x & 63, wid = threadIdx.x >> 6;
  const int wm = wid >> 1, wn = wid & 1;

  f32x4 zero = {0.f, 0.f, 0.f, 0.f};
  f32x4 acc[4][4];
#pragma unroll
  for (int m = 0; m < 4; m++)
#pragma unroll
    for (int n = 0; n < 4; n++) acc[m][n] = zero;

  // T2: global source k-slot pre-swizzle (involution with the LDS read XOR below)
  const int kslot = ((lane & 3) ^ ((lane >> 3) & 3)) * 8;
  const u16* Ag = A + (size_t)(m0 + wid * 32 + (lane >> 2)) * Kd + kslot;
  const u16* Bg = B + (size_t)(n0 + wid * 32 + (lane >> 2)) * Kd + kslot;
  u16* AsW = &As[(wid * 32) * 32];
  u16* BsW = &Bs[(wid * 32) * 32];
  const int rowSkip = 16 * Kd;
  const int fr = lane & 15;
  const int xko = (((lane >> 4) ^ ((fr >> 1) & 3)) << 3);

  for (int kt = 0; kt < Kd; kt += 32) {
    gload16(Ag, AsW);
    gload16(Ag + rowSkip, AsW + 16 * 32);
    gload16(Bg, BsW);
    gload16(Bg + rowSkip, BsW + 16 * 32);
    Ag += 32; Bg += 32;
    __syncthreads();
    bf16x8 af[4], bfr[4];
#pragma unroll
    for (int m = 0; m < 4; m++)
      af[m] = *(const bf16x8*)&As[(wm * 64 + m * 16 + fr) * 32 + xko];
#pragma unroll
    for (int n = 0; n < 4; n++)
      bfr[n] = *(const bf16x8*)&Bs[(wn * 64 + n * 16 + fr) * 32 + xko];
#pragma unroll
    for (int m = 0; m < 4; m++)
#pragma unroll
      for (int n = 0; n < 4; n++)
        acc[m][n] = __builtin_amdgcn_mfma_f32_16x16x32_bf16(af[m], bfr[n], acc[m][n], 0, 0, 0);
    __syncthreads();
  }

  const size_t cb = (size_t)bz * sCb;

  if (MODE == 3) {  // direct f32 path (16 lanes x 4B = full 64B lines already)
#pragma unroll
    for (int m = 0; m < 4; m++) {
#pragma unroll
      for (int n = 0; n < 4; n++) {
        const int col = n0 + wn * 64 + n * 16 + (lane & 15);
        const int rb  = m0 + wm * 64 + m * 16 + ((lane >> 4) << 2);
#pragma unroll
        for (int q = 0; q < 4; q++) {
          const size_t idx = (size_t)(rb + q) * N + col;
          ((float*)C0)[idx] = X[idx] + bf2f(((const u16*)C1)[idx]) + acc[m][n][q];
        }
      }
    }
    return;
  }

  // ---- staged epilogue (MODE 0/2/5): acc -> LDS bf16 tile -> coalesced us8 stores ----
  float sc = 1.0f;
  if (MODE == 2) sc = __expf(scalep[0]) * (1.0f / 1024.0f);
#pragma unroll
  for (int m = 0; m < 4; m++) {
#pragma unroll
    for (int n = 0; n < 4; n++) {
      const int lc = wn * 64 + n * 16 + (lane & 15);
      const int lr = wm * 64 + m * 16 + ((lane >> 4) << 2);
#pragma unroll
      for (int q = 0; q < 4; q++) {
        const float v = acc[m][n][q];
        u16 o;
        if (MODE == 5) o = (n0 < 3072) ? f2bf(v) : f2bf(silu_f(v));
        else if (MODE == 2) o = f2bf(v * sc);
        else o = f2bf(v);
        smem[(lr + q) * 136 + lc] = o;
      }
    }
  }
  __syncthreads();

  u16* Cp;
  size_t base;
  int strideN;
  if (MODE == 5) {
    Cp = (n0 < 3072) ? (u16*)C0 : (u16*)C1;
    strideN = 3072;
    base = (size_t)m0 * 3072 + (size_t)((n0 < 3072) ? n0 : n0 - 3072);
  } else {
    Cp = (u16*)C0;
    strideN = N;
    base = cb + (size_t)m0 * N + n0;
  }
  const int t = threadIdx.x;
  const int seg = t & 15, rr = t >> 4;   // 16 segs x 16 rows per pass
#pragma unroll
  for (int p = 0; p < 8; p++) {
    const int r = p * 16 + rr;
    us8 v = *(const us8*)&smem[r * 136 + seg * 8];
    *(us8*)&Cp[base + (size_t)r * strideN + seg * 8] = v;
  }
}

// ---------- depthwise 3x3 conv + bias + silu, * pre-silu'd gate, in-place into gate ----------
__global__ __launch_bounds__(384)
void k_conv_gate(const u16* __restrict__ val, u16* __restrict__ gate,
                 const u16* __restrict__ wTb, const float* __restrict__ bias) {
  const int tid = threadIdx.x;
  const int m = blockIdx.x * 2 + (tid >= 192);   // wave-uniform (192 = 3 waves)
  const int e0 = (tid % 192) * 16;
  const int j = m & 31, i = (m >> 5) & 31;
  float acc[16];
  {
    const float4* bp = (const float4*)(bias + e0);
    float4 b0 = bp[0], b1 = bp[1], b2 = bp[2], b3 = bp[3];
    acc[0]=b0.x; acc[1]=b0.y; acc[2]=b0.z; acc[3]=b0.w;
    acc[4]=b1.x; acc[5]=b1.y; acc[6]=b1.z; acc[7]=b1.w;
    acc[8]=b2.x; acc[9]=b2.y; acc[10]=b2.z; acc[11]=b2.w;
    acc[12]=b3.x; acc[13]=b3.y; acc[14]=b3.z; acc[15]=b3.w;
  }
  const u16* vb = val + (size_t)m * NDI + e0;
#pragma unroll
  for (int di = -1; di <= 1; di++) {
    if ((unsigned)(i + di) >= 32u) continue;
#pragma unroll
    for (int dj = -1; dj <= 1; dj++) {
      if ((unsigned)(j + dj) >= 32u) continue;
      const u16* vp = vb + (ptrdiff_t)(di * 32 + dj) * NDI;
      us8 v0 = *(const us8*)vp, v1 = *(const us8*)(vp + 8);
      const u16* wp = wTb + ((di + 1) * 3 + (dj + 1)) * NDI + e0;
      us8 w0 = *(const us8*)wp, w1 = *(const us8*)(wp + 8);
#pragma unroll
      for (int q = 0; q < 8; q++) acc[q]     += bf2f(v0[q]) * bf2f(w0[q]);
#pragma unroll
      for (int q = 0; q < 8; q++) acc[8 + q] += bf2f(v1[q]) * bf2f(w1[q]);
    }
  }
  u16* gp = gate + (size_t)m * NDI + e0;
  us8 g0 = *(const us8*)gp, g1 = *(const us8*)(gp + 8);
  us8 o0, o1;
#pragma unroll
  for (int q = 0; q < 8; q++) o0[q] = f2bf(silu_f(acc[q]) * bf2f(g0[q]));
#pragma unroll
  for (int q = 0; q < 8; q++) o1[q] = f2bf(silu_f(acc[8 + q]) * bf2f(g1[q]));
  *(us8*)gp = o0;
  *(us8*)(gp + 8) = o1;
}

// ---------- bf16 transpose: in [NB][NT][NDM] -> out [NB][NDM][NT] ----------
__global__ __launch_bounds__(256)
void k_transpose(const u16* __restrict__ in, u16* __restrict__ out) {
  __shared__ u16 tile[64][65];
  const int d0 = blockIdx.x * 64, t0 = blockIdx.y * 64, b = blockIdx.z;
  const int lx = threadIdx.x & 15, ly = threadIdx.x >> 4;
  const u16* ip = in + ((size_t)b * NTT + t0) * NDM + d0;
#pragma unroll
  for (int p = 0; p < 4; p++) {
    const int r = ly + p * 16;
    ushort4 v = *(const ushort4*)(ip + (size_t)r * NDM + lx * 4);
    tile[r][lx * 4 + 0] = v.x; tile[r][lx * 4 + 1] = v.y;
    tile[r][lx * 4 + 2] = v.z; tile[r][lx * 4 + 3] = v.w;
  }
  __syncthreads();
  u16* op = out + ((size_t)b * NDM + d0) * NTT + t0;
#pragma unroll
  for (int p = 0; p < 4; p++) {
    const int r = ly + p * 16;
    ushort4 v;
    v.x = tile[lx * 4 + 0][r]; v.y = tile[lx * 4 + 1][r];
    v.z = tile[lx * 4 + 2][r]; v.w = tile[lx * 4 + 3][r];
    *(ushort4*)(op + (size_t)r * NTT + lx * 4) = v;
  }
}

// ---------- launch ----------
extern "C" void kernel_launch(void* const* d_in, const int* in_sizes, int n_in,
                              void* d_out, int out_size, void* d_ws, size_t ws_size,
                              hipStream_t stream) {
  const float* x      = (const float*)d_in[0];
  const float* norm_w = (const float*)d_in[1];
  const float* w_proj = (const float*)d_in[2];
  const float* w_gate = (const float*)d_in[3];
  const float* conv_w = (const float*)d_in[4];
  const float* conv_b = (const float*)d_in[5];
  const float* w_out  = (const float*)d_in[6];
  const float* w_k    = (const float*)d_in[7];
  const float* w_v    = (const float*)d_in[8];
  const float* lalpha = (const float*)d_in[9];

  // d_out as scratch for h + bf16 weights (all dead before final GEMM writes d_out)
  char* ob = (char*)d_out;
  u16* h    = (u16*)(ob);                    // 25,165,824 B
  u16* wcat = (u16*)(ob + 25165824);         //  9,437,184  [w_proj ; w_gate] (6144 x 768)
  u16* wob  = (u16*)(ob + 34603008);         //  4,718,592
  u16* wkb  = (u16*)(ob + 39321600);         //  1,179,648
  u16* wvb  = (u16*)(ob + 40501248);         //  1,179,648
  u16* wTb  = (u16*)(ob + 41680896);         //     55,296  (total 41.7MB < 50.3MB)

  char* ws = (char*)d_ws;
  u16* valp  = (u16*)(ws);                   // 100,663,296  [dead after conv]
  u16* gateb = (u16*)(ws + 100663296);       // 100,663,296  silu(gate)->gated [dead after out GEMM]
  u16* outb  = (u16*)(ws);                   //  25,165,824  (valp region, valp dead)
  u16* Kbf   = (u16*)(ws + 25165824);        //  25,165,824
  u16* Vbf   = (u16*)(ws + 50331648);        //  25,165,824
  u16* Kt    = (u16*)(ws + 100663296);       //  25,165,824  (gateb region, gateb dead)
  u16* Vt    = (u16*)(ws + 125829120);       //  25,165,824
  u16* Wt    = (u16*)(ws + 150994944);       //  18,874,368  (max used 169.9MB)

  // weight preprocessing
  k_f32_to_bf16<<<2304, 256, 0, stream>>>(w_proj, wcat,           589824);
  k_f32_to_bf16<<<2304, 256, 0, stream>>>(w_gate, wcat + 2359296, 589824);
  k_f32_to_bf16<<<2304, 256, 0, stream>>>(w_out,  wob, 589824);
  k_f32_to_bf16<<<576,  256, 0, stream>>>(w_k,    wkb, 147456);
  k_f32_to_bf16<<<576,  256, 0, stream>>>(w_v,    wvb, 147456);
  k_convw_t<<<12, 256, 0, stream>>>(conv_w, wTb);

  // h = rmsnorm(x) in bf16
  k_rmsnorm<<<4096, 256, 0, stream>>>(x, norm_w, h);

  // [val_pre | silu(gate_pre)] = h @ [w_proj;w_gate]^T   [16384 x 6144]
  k_gemm_nt<5><<<6144, 256, 0, stream>>>(h, wcat, valp, gateb, nullptr, nullptr,
                                         6144, NDM, 48, 0, 0, 0, 0, 0);
  // gated = silu(conv(val_pre)+b) * siluGate   (in-place into gateb)
  k_conv_gate<<<8192, 384, 0, stream>>>(valp, gateb, wTb, conv_b);

  // out = gated @ w_out^T -> bf16   [16384 x 768]
  k_gemm_nt<0><<<768, 256, 0, stream>>>(gateb, wob, outb, nullptr, nullptr, nullptr,
                                        NDM, NDI, 6, 0, 0, 0, 0, 0);
  // K = h @ w_k^T ; V = out @ w_v^T
  k_gemm_nt<0><<<768, 256, 0, stream>>>(h, wkb, Kbf, nullptr, nullptr, nullptr,
                                        NDM, NDM, 6, 0, 0, 0, 0, 0);
  k_gemm_nt<0><<<768, 256, 0, stream>>>(outb, wvb, Vbf, nullptr, nullptr, nullptr,
                                        NDM, NDM, 6, 0, 0, 0, 0, 0);
  // K^T, V^T per batch: [B, D, T]
  k_transpose<<<dim3(12, 16, 16), 256, 0, stream>>>(Kbf, Kt);
  k_transpose<<<dim3(12, 16, 16), 256, 0, stream>>>(Vbf, Vt);

  // Wt[b][e][d] = (alpha/T) * sum_t V[t,e] K[t,d]
  k_gemm_nt<2><<<dim3(36, 1, 16), 256, 0, stream>>>(Vt, Kt, Wt, nullptr, nullptr, lalpha,
                                                    NDM, NTT, 6,
                                                    (long)NDM * NTT, (long)NDM * NTT,
                                                    (long)NDM * NDM, 0, 0);
  // final: d_out = x + out + sum_d K[t,d] * Wt[e,d]
  k_gemm_nt<3><<<768, 256, 0, stream>>>(Kbf, Wt, d_out, outb, x, nullptr,
                                        NDM, NDM, 6, 0, 0, 0,
                                        NTT, (long)NDM * NDM);
}

// Round 9
// 706.481 us; speedup vs baseline: 1.2131x; 1.0666x over previous
//
#include <hip/hip_runtime.h>
#include <hip/hip_bf16.h>
#include <cstdint>
#include <cstddef>

typedef unsigned short u16;
typedef __attribute__((ext_vector_type(8))) __bf16 bf16x8;
typedef __attribute__((ext_vector_type(4))) float f32x4;
typedef __attribute__((ext_vector_type(8))) unsigned short us8;

#define NDM 768
#define NDI 3072
#define NTT 1024
#define NBB 16
#define NM (NBB*NTT)   // 16384 rows total

// ---------- helpers ----------
__device__ __forceinline__ u16 f2bf(float f) {
  unsigned u = __builtin_bit_cast(unsigned, f);
  u += 0x7fffu + ((u >> 16) & 1u);          // RNE
  return (u16)(u >> 16);
}
__device__ __forceinline__ float bf2f(u16 b) {
  return __builtin_bit_cast(float, ((unsigned)b) << 16);
}
__device__ __forceinline__ float silu_f(float v) {
  return v * (1.0f / (1.0f + __expf(-v)));
}
__device__ __forceinline__ void gload16(const u16* g, u16* l) {
  __builtin_amdgcn_global_load_lds((const __attribute__((address_space(1))) void*)g,
                                   (__attribute__((address_space(3))) void*)l, 16, 0, 0);
}

// ---------- fp32 -> bf16 convert ----------
__global__ __launch_bounds__(256)
void k_f32_to_bf16(const float* __restrict__ in, u16* __restrict__ out, int n4) {
  const int i = blockIdx.x * 256 + threadIdx.x;
  if (i < n4) {
    float4 v = ((const float4*)in)[i];
    ushort4 o;
    o.x = f2bf(v.x); o.y = f2bf(v.y); o.z = f2bf(v.z); o.w = f2bf(v.w);
    ((ushort4*)out)[i] = o;
  }
}

// conv_w [E][3][3] -> wTb [9][E] (bf16)
__global__ __launch_bounds__(256)
void k_convw_t(const float* __restrict__ cw, u16* __restrict__ wTb) {
  const int e = blockIdx.x * 256 + threadIdx.x;
  if (e < NDI) {
#pragma unroll
    for (int t = 0; t < 9; t++) wTb[t * NDI + e] = f2bf(cw[e * 9 + t]);
  }
}

// ---------- RMSNorm: x[M,768] f32 -> h[M,768] bf16 ----------
__global__ __launch_bounds__(256)
void k_rmsnorm(const float* __restrict__ x, const float* __restrict__ w, u16* __restrict__ h) {
  const int row  = blockIdx.x * 4 + (threadIdx.x >> 6);
  const int lane = threadIdx.x & 63;
  const float4* xr = (const float4*)(x + (size_t)row * NDM);
  float4 a = xr[lane], b = xr[lane + 64], c = xr[lane + 128];
  float ss = a.x*a.x + a.y*a.y + a.z*a.z + a.w*a.w
           + b.x*b.x + b.y*b.y + b.z*b.z + b.w*b.w
           + c.x*c.x + c.y*c.y + c.z*c.z + c.w*c.w;
#pragma unroll
  for (int off = 32; off > 0; off >>= 1) ss += __shfl_xor(ss, off);
  const float r = rsqrtf(ss * (1.0f / NDM) + 1e-5f);
  const float4* wr = (const float4*)w;
  float4 wa = wr[lane], wb = wr[lane + 64], wc = wr[lane + 128];
  ushort4 oa, ob, oc;
  oa.x = f2bf(a.x * r * wa.x); oa.y = f2bf(a.y * r * wa.y);
  oa.z = f2bf(a.z * r * wa.z); oa.w = f2bf(a.w * r * wa.w);
  ob.x = f2bf(b.x * r * wb.x); ob.y = f2bf(b.y * r * wb.y);
  ob.z = f2bf(b.z * r * wb.z); ob.w = f2bf(b.w * r * wb.w);
  oc.x = f2bf(c.x * r * wc.x); oc.y = f2bf(c.y * r * wc.y);
  oc.z = f2bf(c.z * r * wc.z); oc.w = f2bf(c.w * r * wc.w);
  ushort4* hr = (ushort4*)(h + (size_t)row * NDM);
  hr[lane] = oa; hr[lane + 64] = ob; hr[lane + 128] = oc;
}

// ---------- 256x256-tile, BK=64, 8-wave, dbuf, counted-vmcnt GEMM (proj+gate fused) ----------
// A [16384][768], B [6144][768] (rows 0-3071 = w_proj, 3072-6143 = w_gate), NT layout.
// Writes Cv (val_pre, raw) or Cg (silu(gate_pre)), both [16384][3072].
// LDS: A [2 dbuf][256 rows][64 cols] bf16 = 64KB, B same at +32768 u16 -> 128 KiB total.
// Swizzle: 16B-slot p at row r holds logical slot p ^ (r&7) (both-sides involution:
// pre-swizzled GLOBAL source + XOR on LDS reads; linear gload dest per rule 21).
// Row stride 128B = 0 mod 32 banks, so slot-spread = full 32-bank coverage per 8-lane group.
// vmcnt discipline (T4): 8 gloads per K-tile per wave; invariant at iter t: outstanding =
// stages {t, t+1}; vmcnt(8) completes t, leaves t+1 in flight. Drain to 0 only at t=11.
__device__ __forceinline__ void stage8(const u16* Asrc, const u16* Bsrc, u16* smem,
                                       int cur, int wid) {
  u16* Ad = smem + cur * 16384 + wid * 512;          // wave-uniform base; HW adds lane*16B
  u16* Bd = smem + 32768 + cur * 16384 + wid * 512;
#pragma unroll
  for (int i = 0; i < 4; i++) {
    gload16(Asrc + i * 49152, Ad + i * 4096);        // 64 rows * 768 = 49152 u16 per issue
    gload16(Bsrc + i * 49152, Bd + i * 4096);
  }
}

__global__ __launch_bounds__(512, 2)
void k_gemm8p(const u16* __restrict__ A, const u16* __restrict__ B,
              u16* __restrict__ Cv, u16* __restrict__ Cg) {
  __shared__ u16 smem[65536];                        // 128 KiB
  const int nwg = gridDim.x;                         // 1536 (divisible by 8)
  const int id = blockIdx.x;
  const int sid = ((nwg & 7) == 0) ? ((id & 7) * (nwg >> 3) + (id >> 3)) : id;
  const int mt = sid / 24, ntile = sid - mt * 24;
  const int m0 = mt * 256, n0 = ntile * 256;

  const int tid = threadIdx.x;
  const int lane = tid & 63, wid = tid >> 6;
  const int wm = wid >> 2, wn = wid & 3;             // 2 (M) x 4 (N) waves
  const int fr = lane & 15, l4 = lane >> 4;

  // staging source: thread covers (row = i*64 + tid/8, physslot = tid&7);
  // logical col16 = physslot ^ (row&7); (row&7) == ((tid>>3)&7) since 64 = 0 mod 8
  const int srow = tid >> 3;
  const int sslot = (tid & 7) ^ (srow & 7);
  const u16* Asrc = A + (size_t)(m0 + srow) * 768 + sslot * 8;
  const u16* Bsrc = B + (size_t)(n0 + srow) * 768 + sslot * 8;

  f32x4 acc[8][4];
#pragma unroll
  for (int m = 0; m < 8; m++)
#pragma unroll
    for (int n = 0; n < 4; n++) acc[m][n] = (f32x4){0.f, 0.f, 0.f, 0.f};

  stage8(Asrc,      Bsrc,      smem, 0, wid);        // K-tile 0
  stage8(Asrc + 64, Bsrc + 64, smem, 1, wid);        // K-tile 1

  int cur = 0;
#pragma unroll 1
  for (int t = 0; t < 12; t++) {                     // 12 K-tiles of 64 (K=768)
    if (t == 11) asm volatile("s_waitcnt vmcnt(0)" ::: "memory");
    else         asm volatile("s_waitcnt vmcnt(8)" ::: "memory");
    __builtin_amdgcn_s_barrier();                    // buf[cur] staged by ALL waves

    const u16* Abuf = smem + cur * 16384;
    const u16* Bbuf = smem + 32768 + cur * 16384;

    bf16x8 bfrag[4][2];
#pragma unroll
    for (int nf = 0; nf < 4; nf++) {
      const int brow = wn * 64 + nf * 16 + fr;
#pragma unroll
      for (int s = 0; s < 2; s++)
        bfrag[nf][s] = *(const bf16x8*)&Bbuf[brow * 64 + (((s << 2) + l4) ^ (brow & 7)) * 8];
    }
#pragma unroll
    for (int mf = 0; mf < 8; mf++) {
      const int arow = wm * 128 + mf * 16 + fr;
      bf16x8 a0 = *(const bf16x8*)&Abuf[arow * 64 + ((l4)     ^ (arow & 7)) * 8];
      bf16x8 a1 = *(const bf16x8*)&Abuf[arow * 64 + ((4 + l4) ^ (arow & 7)) * 8];
#pragma unroll
      for (int nf = 0; nf < 4; nf++) {
        acc[mf][nf] = __builtin_amdgcn_mfma_f32_16x16x32_bf16(a0, bfrag[nf][0], acc[mf][nf], 0, 0, 0);
        acc[mf][nf] = __builtin_amdgcn_mfma_f32_16x16x32_bf16(a1, bfrag[nf][1], acc[mf][nf], 0, 0, 0);
      }
    }
    asm volatile("s_waitcnt lgkmcnt(0)" ::: "memory");  // my reads of buf[cur] done
    __builtin_amdgcn_s_barrier();                        // ALL waves done reading buf[cur]
    if (t < 10) stage8(Asrc + (t + 2) * 64, Bsrc + (t + 2) * 64, smem, cur, wid);
    cur ^= 1;
  }

  // epilogue: direct stores (round-4 pattern, measured equivalent to staged)
  const bool gate = (n0 >= 3072);
  u16* Cp = gate ? Cg : Cv;
  const int cb = gate ? n0 - 3072 : n0;
#pragma unroll
  for (int mf = 0; mf < 8; mf++) {
#pragma unroll
    for (int nf = 0; nf < 4; nf++) {
      const int col = cb + wn * 64 + nf * 16 + fr;
      const int rb  = m0 + wm * 128 + mf * 16 + (l4 << 2);
#pragma unroll
      for (int q = 0; q < 4; q++) {
        float v = acc[mf][nf][q];
        if (gate) v = silu_f(v);
        Cp[(size_t)(rb + q) * 3072 + col] = f2bf(v);
      }
    }
  }
}

// ---------- NT GEMM, 128x128 tile, BK=32, 4 waves (m97 structure), 1D grid + XCD swizzle ----------
// MODE 0: bf16 store -> C0 (stride N)
// MODE 2: bf16 store scaled by expf(*scalep)/1024 -> C0
// MODE 3: f32 store  -> C0 = X + bf16(C1) + acc   (stride N, direct)
template <int MODE>
__global__ __launch_bounds__(256)
void k_gemm_nt(const u16* __restrict__ A, const u16* __restrict__ B,
               void* __restrict__ C0, void* __restrict__ C1,
               const float* __restrict__ X, const float* __restrict__ scalep,
               int N, int Kd, int nTiles,
               long sAb, long sBb, long sCb, int mPerBatchB, long sBm) {
  __shared__ u16 smem[128 * 136];
  u16* As = smem;
  u16* Bs = smem + 4096;
  const int bz = blockIdx.z;
  A += (size_t)bz * sAb;
  B += (size_t)bz * sBb;

  const int nwg = gridDim.x;
  const int id = blockIdx.x;
  const int sid = ((nwg & 7) == 0) ? ((id & 7) * (nwg >> 3) + (id >> 3)) : id;
  const int mt = sid / nTiles, nt = sid - mt * nTiles;
  const int m0 = mt * 128, n0 = nt * 128;
  if (mPerBatchB > 0) B += (size_t)(m0 / mPerBatchB) * sBm;

  const int lane = threadIdx.x & 63, wid = threadIdx.x >> 6;
  const int wm = wid >> 1, wn = wid & 1;

  f32x4 zero = {0.f, 0.f, 0.f, 0.f};
  f32x4 acc[4][4];
#pragma unroll
  for (int m = 0; m < 4; m++)
#pragma unroll
    for (int n = 0; n < 4; n++) acc[m][n] = zero;

  const int kslot = ((lane & 3) ^ ((lane >> 3) & 3)) * 8;
  const u16* Ag = A + (size_t)(m0 + wid * 32 + (lane >> 2)) * Kd + kslot;
  const u16* Bg = B + (size_t)(n0 + wid * 32 + (lane >> 2)) * Kd + kslot;
  u16* AsW = &As[(wid * 32) * 32];
  u16* BsW = &Bs[(wid * 32) * 32];
  const int rowSkip = 16 * Kd;
  const int fr = lane & 15;
  const int xko = (((lane >> 4) ^ ((fr >> 1) & 3)) << 3);

  for (int kt = 0; kt < Kd; kt += 32) {
    gload16(Ag, AsW);
    gload16(Ag + rowSkip, AsW + 16 * 32);
    gload16(Bg, BsW);
    gload16(Bg + rowSkip, BsW + 16 * 32);
    Ag += 32; Bg += 32;
    __syncthreads();
    bf16x8 af[4], bfr[4];
#pragma unroll
    for (int m = 0; m < 4; m++)
      af[m] = *(const bf16x8*)&As[(wm * 64 + m * 16 + fr) * 32 + xko];
#pragma unroll
    for (int n = 0; n < 4; n++)
      bfr[n] = *(const bf16x8*)&Bs[(wn * 64 + n * 16 + fr) * 32 + xko];
#pragma unroll
    for (int m = 0; m < 4; m++)
#pragma unroll
      for (int n = 0; n < 4; n++)
        acc[m][n] = __builtin_amdgcn_mfma_f32_16x16x32_bf16(af[m], bfr[n], acc[m][n], 0, 0, 0);
    __syncthreads();
  }

  const size_t cb = (size_t)bz * sCb;

  if (MODE == 3) {
#pragma unroll
    for (int m = 0; m < 4; m++) {
#pragma unroll
      for (int n = 0; n < 4; n++) {
        const int col = n0 + wn * 64 + n * 16 + (lane & 15);
        const int rb  = m0 + wm * 64 + m * 16 + ((lane >> 4) << 2);
#pragma unroll
        for (int q = 0; q < 4; q++) {
          const size_t idx = (size_t)(rb + q) * N + col;
          ((float*)C0)[idx] = X[idx] + bf2f(((const u16*)C1)[idx]) + acc[m][n][q];
        }
      }
    }
    return;
  }

  float sc = 1.0f;
  if (MODE == 2) sc = __expf(scalep[0]) * (1.0f / 1024.0f);
#pragma unroll
  for (int m = 0; m < 4; m++) {
#pragma unroll
    for (int n = 0; n < 4; n++) {
      const int lc = wn * 64 + n * 16 + (lane & 15);
      const int lr = wm * 64 + m * 16 + ((lane >> 4) << 2);
#pragma unroll
      for (int q = 0; q < 4; q++) {
        const float v = acc[m][n][q];
        smem[(lr + q) * 136 + lc] = (MODE == 2) ? f2bf(v * sc) : f2bf(v);
      }
    }
  }
  __syncthreads();

  u16* Cp = (u16*)C0;
  const size_t base = cb + (size_t)m0 * N + n0;
  const int t = threadIdx.x;
  const int seg = t & 15, rr = t >> 4;
#pragma unroll
  for (int p = 0; p < 8; p++) {
    const int r = p * 16 + rr;
    us8 v = *(const us8*)&smem[r * 136 + seg * 8];
    *(us8*)&Cp[base + (size_t)r * N + seg * 8] = v;
  }
}

// ---------- depthwise 3x3 conv + bias + silu, * pre-silu'd gate, in-place into gate ----------
__global__ __launch_bounds__(384)
void k_conv_gate(const u16* __restrict__ val, u16* __restrict__ gate,
                 const u16* __restrict__ wTb, const float* __restrict__ bias) {
  const int tid = threadIdx.x;
  const int m = blockIdx.x * 2 + (tid >= 192);
  const int e0 = (tid % 192) * 16;
  const int j = m & 31, i = (m >> 5) & 31;
  float acc[16];
  {
    const float4* bp = (const float4*)(bias + e0);
    float4 b0 = bp[0], b1 = bp[1], b2 = bp[2], b3 = bp[3];
    acc[0]=b0.x; acc[1]=b0.y; acc[2]=b0.z; acc[3]=b0.w;
    acc[4]=b1.x; acc[5]=b1.y; acc[6]=b1.z; acc[7]=b1.w;
    acc[8]=b2.x; acc[9]=b2.y; acc[10]=b2.z; acc[11]=b2.w;
    acc[12]=b3.x; acc[13]=b3.y; acc[14]=b3.z; acc[15]=b3.w;
  }
  const u16* vb = val + (size_t)m * NDI + e0;
#pragma unroll
  for (int di = -1; di <= 1; di++) {
    if ((unsigned)(i + di) >= 32u) continue;
#pragma unroll
    for (int dj = -1; dj <= 1; dj++) {
      if ((unsigned)(j + dj) >= 32u) continue;
      const u16* vp = vb + (ptrdiff_t)(di * 32 + dj) * NDI;
      us8 v0 = *(const us8*)vp, v1 = *(const us8*)(vp + 8);
      const u16* wp = wTb + ((di + 1) * 3 + (dj + 1)) * NDI + e0;
      us8 w0 = *(const us8*)wp, w1 = *(const us8*)(wp + 8);
#pragma unroll
      for (int q = 0; q < 8; q++) acc[q]     += bf2f(v0[q]) * bf2f(w0[q]);
#pragma unroll
      for (int q = 0; q < 8; q++) acc[8 + q] += bf2f(v1[q]) * bf2f(w1[q]);
    }
  }
  u16* gp = gate + (size_t)m * NDI + e0;
  us8 g0 = *(const us8*)gp, g1 = *(const us8*)(gp + 8);
  us8 o0, o1;
#pragma unroll
  for (int q = 0; q < 8; q++) o0[q] = f2bf(silu_f(acc[q]) * bf2f(g0[q]));
#pragma unroll
  for (int q = 0; q < 8; q++) o1[q] = f2bf(silu_f(acc[8 + q]) * bf2f(g1[q]));
  *(us8*)gp = o0;
  *(us8*)(gp + 8) = o1;
}

// ---------- bf16 transpose: in [NB][NT][NDM] -> out [NB][NDM][NT] ----------
__global__ __launch_bounds__(256)
void k_transpose(const u16* __restrict__ in, u16* __restrict__ out) {
  __shared__ u16 tile[64][65];
  const int d0 = blockIdx.x * 64, t0 = blockIdx.y * 64, b = blockIdx.z;
  const int lx = threadIdx.x & 15, ly = threadIdx.x >> 4;
  const u16* ip = in + ((size_t)b * NTT + t0) * NDM + d0;
#pragma unroll
  for (int p = 0; p < 4; p++) {
    const int r = ly + p * 16;
    ushort4 v = *(const ushort4*)(ip + (size_t)r * NDM + lx * 4);
    tile[r][lx * 4 + 0] = v.x; tile[r][lx * 4 + 1] = v.y;
    tile[r][lx * 4 + 2] = v.z; tile[r][lx * 4 + 3] = v.w;
  }
  __syncthreads();
  u16* op = out + ((size_t)b * NDM + d0) * NTT + t0;
#pragma unroll
  for (int p = 0; p < 4; p++) {
    const int r = ly + p * 16;
    ushort4 v;
    v.x = tile[lx * 4 + 0][r]; v.y = tile[lx * 4 + 1][r];
    v.z = tile[lx * 4 + 2][r]; v.w = tile[lx * 4 + 3][r];
    *(ushort4*)(op + (size_t)r * NTT + lx * 4) = v;
  }
}

// ---------- launch ----------
extern "C" void kernel_launch(void* const* d_in, const int* in_sizes, int n_in,
                              void* d_out, int out_size, void* d_ws, size_t ws_size,
                              hipStream_t stream) {
  const float* x      = (const float*)d_in[0];
  const float* norm_w = (const float*)d_in[1];
  const float* w_proj = (const float*)d_in[2];
  const float* w_gate = (const float*)d_in[3];
  const float* conv_w = (const float*)d_in[4];
  const float* conv_b = (const float*)d_in[5];
  const float* w_out  = (const float*)d_in[6];
  const float* w_k    = (const float*)d_in[7];
  const float* w_v    = (const float*)d_in[8];
  const float* lalpha = (const float*)d_in[9];

  // d_out as scratch for h + bf16 weights (all dead before final GEMM writes d_out)
  char* ob = (char*)d_out;
  u16* h    = (u16*)(ob);                    // 25,165,824 B
  u16* wcat = (u16*)(ob + 25165824);         //  9,437,184  [w_proj ; w_gate] (6144 x 768)
  u16* wob  = (u16*)(ob + 34603008);         //  4,718,592
  u16* wkb  = (u16*)(ob + 39321600);         //  1,179,648
  u16* wvb  = (u16*)(ob + 40501248);         //  1,179,648
  u16* wTb  = (u16*)(ob + 41680896);         //     55,296  (total 41.7MB < 50.3MB)

  char* ws = (char*)d_ws;
  u16* valp  = (u16*)(ws);                   // 100,663,296  [dead after conv]
  u16* gateb = (u16*)(ws + 100663296);       // 100,663,296  silu(gate)->gated [dead after out GEMM]
  u16* outb  = (u16*)(ws);                   //  25,165,824  (valp region, valp dead)
  u16* Kbf   = (u16*)(ws + 25165824);        //  25,165,824
  u16* Vbf   = (u16*)(ws + 50331648);        //  25,165,824
  u16* Kt    = (u16*)(ws + 100663296);       //  25,165,824  (gateb region, gateb dead)
  u16* Vt    = (u16*)(ws + 125829120);       //  25,165,824
  u16* Wt    = (u16*)(ws + 150994944);       //  18,874,368  (max used 169.9MB)

  // weight preprocessing
  k_f32_to_bf16<<<2304, 256, 0, stream>>>(w_proj, wcat,           589824);
  k_f32_to_bf16<<<2304, 256, 0, stream>>>(w_gate, wcat + 2359296, 589824);
  k_f32_to_bf16<<<2304, 256, 0, stream>>>(w_out,  wob, 589824);
  k_f32_to_bf16<<<576,  256, 0, stream>>>(w_k,    wkb, 147456);
  k_f32_to_bf16<<<576,  256, 0, stream>>>(w_v,    wvb, 147456);
  k_convw_t<<<12, 256, 0, stream>>>(conv_w, wTb);

  // h = rmsnorm(x) in bf16
  k_rmsnorm<<<4096, 256, 0, stream>>>(x, norm_w, h);

  // [val_pre | silu(gate_pre)] = h @ [w_proj;w_gate]^T  -- 256^2 8-wave pipelined GEMM
  k_gemm8p<<<1536, 512, 0, stream>>>(h, wcat, valp, gateb);

  // gated = silu(conv(val_pre)+b) * siluGate   (in-place into gateb)
  k_conv_gate<<<8192, 384, 0, stream>>>(valp, gateb, wTb, conv_b);

  // out = gated @ w_out^T -> bf16   [16384 x 768]
  k_gemm_nt<0><<<768, 256, 0, stream>>>(gateb, wob, outb, nullptr, nullptr, nullptr,
                                        NDM, NDI, 6, 0, 0, 0, 0, 0);
  // K = h @ w_k^T ; V = out @ w_v^T
  k_gemm_nt<0><<<768, 256, 0, stream>>>(h, wkb, Kbf, nullptr, nullptr, nullptr,
                                        NDM, NDM, 6, 0, 0, 0, 0, 0);
  k_gemm_nt<0><<<768, 256, 0, stream>>>(outb, wvb, Vbf, nullptr, nullptr, nullptr,
                                        NDM, NDM, 6, 0, 0, 0, 0, 0);
  // K^T, V^T per batch: [B, D, T]
  k_transpose<<<dim3(12, 16, 16), 256, 0, stream>>>(Kbf, Kt);
  k_transpose<<<dim3(12, 16, 16), 256, 0, stream>>>(Vbf, Vt);

  // Wt[b][e][d] = (alpha/T) * sum_t V[t,e] K[t,d]
  k_gemm_nt<2><<<dim3(36, 1, 16), 256, 0, stream>>>(Vt, Kt, Wt, nullptr, nullptr, lalpha,
                                                    NDM, NTT, 6,
                                                    (long)NDM * NTT, (long)NDM * NTT,
                                                    (long)NDM * NDM, 0, 0);
  // final: d_out = x + out + sum_d K[t,d] * Wt[e,d]
  k_gemm_nt<3><<<768, 256, 0, stream>>>(Kbf, Wt, d_out, outb, x, nullptr,
                                        NDM, NDM, 6, 0, 0, 0,
                                        NTT, (long)NDM * NDM);
}

// Round 10
// 701.345 us; speedup vs baseline: 1.2220x; 1.0073x over previous
//
#include <hip/hip_runtime.h>
#include <hip/hip_bf16.h>
#include <cstdint>
#include <cstddef>

typedef unsigned short u16;
typedef __attribute__((ext_vector_type(8))) __bf16 bf16x8;
typedef __attribute__((ext_vector_type(4))) float f32x4;
typedef __attribute__((ext_vector_type(8))) unsigned short us8;

#define NDM 768
#define NDI 3072
#define NTT 1024
#define NBB 16
#define NM (NBB*NTT)   // 16384 rows total

// ---------- helpers ----------
__device__ __forceinline__ u16 f2bf(float f) {
  unsigned u = __builtin_bit_cast(unsigned, f);
  u += 0x7fffu + ((u >> 16) & 1u);          // RNE
  return (u16)(u >> 16);
}
__device__ __forceinline__ float bf2f(u16 b) {
  return __builtin_bit_cast(float, ((unsigned)b) << 16);
}
__device__ __forceinline__ float silu_f(float v) {
  return v * (1.0f / (1.0f + __expf(-v)));
}
__device__ __forceinline__ void gload16(const u16* g, u16* l) {
  __builtin_amdgcn_global_load_lds((const __attribute__((address_space(1))) void*)g,
                                   (__attribute__((address_space(3))) void*)l, 16, 0, 0);
}

// ---------- fp32 -> bf16 convert ----------
__global__ __launch_bounds__(256)
void k_f32_to_bf16(const float* __restrict__ in, u16* __restrict__ out, int n4) {
  const int i = blockIdx.x * 256 + threadIdx.x;
  if (i < n4) {
    float4 v = ((const float4*)in)[i];
    ushort4 o;
    o.x = f2bf(v.x); o.y = f2bf(v.y); o.z = f2bf(v.z); o.w = f2bf(v.w);
    ((ushort4*)out)[i] = o;
  }
}

// conv_w [E][3][3] -> wTb [9][E] (bf16)
__global__ __launch_bounds__(256)
void k_convw_t(const float* __restrict__ cw, u16* __restrict__ wTb) {
  const int e = blockIdx.x * 256 + threadIdx.x;
  if (e < NDI) {
#pragma unroll
    for (int t = 0; t < 9; t++) wTb[t * NDI + e] = f2bf(cw[e * 9 + t]);
  }
}

// ---------- RMSNorm: x[M,768] f32 -> h[M,768] bf16 ----------
__global__ __launch_bounds__(256)
void k_rmsnorm(const float* __restrict__ x, const float* __restrict__ w, u16* __restrict__ h) {
  const int row  = blockIdx.x * 4 + (threadIdx.x >> 6);
  const int lane = threadIdx.x & 63;
  const float4* xr = (const float4*)(x + (size_t)row * NDM);
  float4 a = xr[lane], b = xr[lane + 64], c = xr[lane + 128];
  float ss = a.x*a.x + a.y*a.y + a.z*a.z + a.w*a.w
           + b.x*b.x + b.y*b.y + b.z*b.z + b.w*b.w
           + c.x*c.x + c.y*c.y + c.z*c.z + c.w*c.w;
#pragma unroll
  for (int off = 32; off > 0; off >>= 1) ss += __shfl_xor(ss, off);
  const float r = rsqrtf(ss * (1.0f / NDM) + 1e-5f);
  const float4* wr = (const float4*)w;
  float4 wa = wr[lane], wb = wr[lane + 64], wc = wr[lane + 128];
  ushort4 oa, ob, oc;
  oa.x = f2bf(a.x * r * wa.x); oa.y = f2bf(a.y * r * wa.y);
  oa.z = f2bf(a.z * r * wa.z); oa.w = f2bf(a.w * r * wa.w);
  ob.x = f2bf(b.x * r * wb.x); ob.y = f2bf(b.y * r * wb.y);
  ob.z = f2bf(b.z * r * wb.z); ob.w = f2bf(b.w * r * wb.w);
  oc.x = f2bf(c.x * r * wc.x); oc.y = f2bf(c.y * r * wc.y);
  oc.z = f2bf(c.z * r * wc.z); oc.w = f2bf(c.w * r * wc.w);
  ushort4* hr = (ushort4*)(h + (size_t)row * NDM);
  hr[lane] = oa; hr[lane + 64] = ob; hr[lane + 128] = oc;
}

// ---------- 256x256-tile, BK=64, 8-wave, dbuf, counted-vmcnt GEMM (generalized) ----------
// Same verified sync structure as round-9's k_gemm8p (vmcnt ledger: prologue 16 outstanding,
// per-iter vmcnt(8) completes tile t leaving t+1 in flight, drain at t=nkt-1; stage(t+2)
// into buf[cur] only after the second barrier). Parameter changes only (Kd/N/batch strides).
// Swizzle: 16B-slot p at row r holds logical slot p ^ (r&7), via pre-swizzled GLOBAL source
// + XOR on LDS reads (rule 21). Bank conflicts measured 0.
// MODE 0: bf16 -> C0 stride N.           MODE 2: bf16 * expf(*scalep)/1024 -> C0 stride N.
// MODE 3: f32 -> C0 = X + bf16(C1) + acc, stride N.
// MODE 5: cols<3072 -> C0 bf16; cols>=3072 -> C1 silu bf16 (both stride 3072).
__device__ __forceinline__ void stage8k(const u16* Asrc, const u16* Bsrc, u16* smem,
                                        int cur, int wid, int Kd) {
  u16* Ad = smem + cur * 16384 + wid * 512;          // wave-uniform base; HW adds lane*16B
  u16* Bd = smem + 32768 + cur * 16384 + wid * 512;
  const size_t blk = (size_t)64 * Kd;                // 64 rows per issue
#pragma unroll
  for (int i = 0; i < 4; i++) {
    gload16(Asrc + i * blk, Ad + i * 4096);
    gload16(Bsrc + i * blk, Bd + i * 4096);
  }
}

template <int MODE>
__global__ __launch_bounds__(512, 2)
void k_g8(const u16* __restrict__ A, const u16* __restrict__ B,
          void* __restrict__ C0, void* __restrict__ C1,
          const float* __restrict__ X, const float* __restrict__ scalep,
          int N, int Kd, int nkt, int nTiles,
          long sAb, long sBb, long sCb, int mPerBatchB, long sBm) {
  __shared__ u16 smem[65536];                        // 128 KiB
  const int bz = blockIdx.z;
  A += (size_t)bz * sAb;
  B += (size_t)bz * sBb;
  const int nwg = gridDim.x;
  const int id = blockIdx.x;
  const int sid = ((nwg & 7) == 0) ? ((id & 7) * (nwg >> 3) + (id >> 3)) : id;
  const int mt = sid / nTiles, ntile = sid - mt * nTiles;
  const int m0 = mt * 256, n0 = ntile * 256;
  if (mPerBatchB > 0) B += (size_t)(m0 / mPerBatchB) * sBm;

  const int tid = threadIdx.x;
  const int lane = tid & 63, wid = tid >> 6;
  const int wm = wid >> 2, wn = wid & 3;             // 2 (M) x 4 (N) waves
  const int fr = lane & 15, l4 = lane >> 4;

  // staging source: thread covers (row = i*64 + tid/8, physslot = tid&7);
  // logical col16 = physslot ^ (row&7)
  const int srow = tid >> 3;
  const int sslot = (tid & 7) ^ (srow & 7);
  const u16* Asrc = A + (size_t)(m0 + srow) * Kd + sslot * 8;
  const u16* Bsrc = B + (size_t)(n0 + srow) * Kd + sslot * 8;

  f32x4 acc[8][4];
#pragma unroll
  for (int m = 0; m < 8; m++)
#pragma unroll
    for (int n = 0; n < 4; n++) acc[m][n] = (f32x4){0.f, 0.f, 0.f, 0.f};

  stage8k(Asrc,      Bsrc,      smem, 0, wid, Kd);   // K-tile 0
  stage8k(Asrc + 64, Bsrc + 64, smem, 1, wid, Kd);   // K-tile 1

  int cur = 0;
#pragma unroll 1
  for (int t = 0; t < nkt; t++) {
    if (t == nkt - 1) asm volatile("s_waitcnt vmcnt(0)" ::: "memory");
    else              asm volatile("s_waitcnt vmcnt(8)" ::: "memory");
    __builtin_amdgcn_s_barrier();                    // buf[cur] staged by ALL waves

    const u16* Abuf = smem + cur * 16384;
    const u16* Bbuf = smem + 32768 + cur * 16384;

    bf16x8 bfrag[4][2];
#pragma unroll
    for (int nf = 0; nf < 4; nf++) {
      const int brow = wn * 64 + nf * 16 + fr;
#pragma unroll
      for (int s = 0; s < 2; s++)
        bfrag[nf][s] = *(const bf16x8*)&Bbuf[brow * 64 + (((s << 2) + l4) ^ (brow & 7)) * 8];
    }
#pragma unroll
    for (int mf = 0; mf < 8; mf++) {
      const int arow = wm * 128 + mf * 16 + fr;
      bf16x8 a0 = *(const bf16x8*)&Abuf[arow * 64 + ((l4)     ^ (arow & 7)) * 8];
      bf16x8 a1 = *(const bf16x8*)&Abuf[arow * 64 + ((4 + l4) ^ (arow & 7)) * 8];
#pragma unroll
      for (int nf = 0; nf < 4; nf++) {
        acc[mf][nf] = __builtin_amdgcn_mfma_f32_16x16x32_bf16(a0, bfrag[nf][0], acc[mf][nf], 0, 0, 0);
        acc[mf][nf] = __builtin_amdgcn_mfma_f32_16x16x32_bf16(a1, bfrag[nf][1], acc[mf][nf], 0, 0, 0);
      }
    }
    asm volatile("s_waitcnt lgkmcnt(0)" ::: "memory");  // my reads of buf[cur] done
    __builtin_amdgcn_s_barrier();                        // ALL waves done reading buf[cur]
    if (t < nkt - 2) stage8k(Asrc + (size_t)(t + 2) * 64, Bsrc + (size_t)(t + 2) * 64,
                             smem, cur, wid, Kd);
    cur ^= 1;
  }

  // ---- epilogue ----
  float sc = 1.0f;
  if (MODE == 2) sc = __expf(scalep[0]) * (1.0f / 1024.0f);
  const size_t cb = (size_t)bz * sCb;
#pragma unroll
  for (int mf = 0; mf < 8; mf++) {
#pragma unroll
    for (int nf = 0; nf < 4; nf++) {
      const int lc = wn * 64 + nf * 16 + fr;
      const int rb = m0 + wm * 128 + mf * 16 + (l4 << 2);
#pragma unroll
      for (int q = 0; q < 4; q++) {
        float v = acc[mf][nf][q];
        if (MODE == 0) {
          ((u16*)C0)[cb + (size_t)(rb + q) * N + n0 + lc] = f2bf(v);
        } else if (MODE == 2) {
          ((u16*)C0)[cb + (size_t)(rb + q) * N + n0 + lc] = f2bf(v * sc);
        } else if (MODE == 3) {
          const size_t idx = (size_t)(rb + q) * N + n0 + lc;
          ((float*)C0)[idx] = X[idx] + bf2f(((const u16*)C1)[idx]) + v;
        } else { // MODE 5
          const int gc = n0 + lc;
          if (gc < 3072) ((u16*)C0)[(size_t)(rb + q) * 3072 + gc] = f2bf(v);
          else           ((u16*)C1)[(size_t)(rb + q) * 3072 + gc - 3072] = f2bf(silu_f(v));
        }
      }
    }
  }
}

// ---------- depthwise 3x3 conv + bias + silu, * pre-silu'd gate, in-place into gate ----------
__global__ __launch_bounds__(384)
void k_conv_gate(const u16* __restrict__ val, u16* __restrict__ gate,
                 const u16* __restrict__ wTb, const float* __restrict__ bias) {
  const int tid = threadIdx.x;
  const int m = blockIdx.x * 2 + (tid >= 192);
  const int e0 = (tid % 192) * 16;
  const int j = m & 31, i = (m >> 5) & 31;
  float acc[16];
  {
    const float4* bp = (const float4*)(bias + e0);
    float4 b0 = bp[0], b1 = bp[1], b2 = bp[2], b3 = bp[3];
    acc[0]=b0.x; acc[1]=b0.y; acc[2]=b0.z; acc[3]=b0.w;
    acc[4]=b1.x; acc[5]=b1.y; acc[6]=b1.z; acc[7]=b1.w;
    acc[8]=b2.x; acc[9]=b2.y; acc[10]=b2.z; acc[11]=b2.w;
    acc[12]=b3.x; acc[13]=b3.y; acc[14]=b3.z; acc[15]=b3.w;
  }
  const u16* vb = val + (size_t)m * NDI + e0;
#pragma unroll
  for (int di = -1; di <= 1; di++) {
    if ((unsigned)(i + di) >= 32u) continue;
#pragma unroll
    for (int dj = -1; dj <= 1; dj++) {
      if ((unsigned)(j + dj) >= 32u) continue;
      const u16* vp = vb + (ptrdiff_t)(di * 32 + dj) * NDI;
      us8 v0 = *(const us8*)vp, v1 = *(const us8*)(vp + 8);
      const u16* wp = wTb + ((di + 1) * 3 + (dj + 1)) * NDI + e0;
      us8 w0 = *(const us8*)wp, w1 = *(const us8*)(wp + 8);
#pragma unroll
      for (int q = 0; q < 8; q++) acc[q]     += bf2f(v0[q]) * bf2f(w0[q]);
#pragma unroll
      for (int q = 0; q < 8; q++) acc[8 + q] += bf2f(v1[q]) * bf2f(w1[q]);
    }
  }
  u16* gp = gate + (size_t)m * NDI + e0;
  us8 g0 = *(const us8*)gp, g1 = *(const us8*)(gp + 8);
  us8 o0, o1;
#pragma unroll
  for (int q = 0; q < 8; q++) o0[q] = f2bf(silu_f(acc[q]) * bf2f(g0[q]));
#pragma unroll
  for (int q = 0; q < 8; q++) o1[q] = f2bf(silu_f(acc[8 + q]) * bf2f(g1[q]));
  *(us8*)gp = o0;
  *(us8*)(gp + 8) = o1;
}

// ---------- bf16 transpose: in [NB][NT][NDM] -> out [NB][NDM][NT] ----------
__global__ __launch_bounds__(256)
void k_transpose(const u16* __restrict__ in, u16* __restrict__ out) {
  __shared__ u16 tile[64][65];
  const int d0 = blockIdx.x * 64, t0 = blockIdx.y * 64, b = blockIdx.z;
  const int lx = threadIdx.x & 15, ly = threadIdx.x >> 4;
  const u16* ip = in + ((size_t)b * NTT + t0) * NDM + d0;
#pragma unroll
  for (int p = 0; p < 4; p++) {
    const int r = ly + p * 16;
    ushort4 v = *(const ushort4*)(ip + (size_t)r * NDM + lx * 4);
    tile[r][lx * 4 + 0] = v.x; tile[r][lx * 4 + 1] = v.y;
    tile[r][lx * 4 + 2] = v.z; tile[r][lx * 4 + 3] = v.w;
  }
  __syncthreads();
  u16* op = out + ((size_t)b * NDM + d0) * NTT + t0;
#pragma unroll
  for (int p = 0; p < 4; p++) {
    const int r = ly + p * 16;
    ushort4 v;
    v.x = tile[lx * 4 + 0][r]; v.y = tile[lx * 4 + 1][r];
    v.z = tile[lx * 4 + 2][r]; v.w = tile[lx * 4 + 3][r];
    *(ushort4*)(op + (size_t)r * NTT + lx * 4) = v;
  }
}

// ---------- launch ----------
extern "C" void kernel_launch(void* const* d_in, const int* in_sizes, int n_in,
                              void* d_out, int out_size, void* d_ws, size_t ws_size,
                              hipStream_t stream) {
  const float* x      = (const float*)d_in[0];
  const float* norm_w = (const float*)d_in[1];
  const float* w_proj = (const float*)d_in[2];
  const float* w_gate = (const float*)d_in[3];
  const float* conv_w = (const float*)d_in[4];
  const float* conv_b = (const float*)d_in[5];
  const float* w_out  = (const float*)d_in[6];
  const float* w_k    = (const float*)d_in[7];
  const float* w_v    = (const float*)d_in[8];
  const float* lalpha = (const float*)d_in[9];

  // d_out as scratch for h + bf16 weights (all dead before final GEMM writes d_out)
  char* ob = (char*)d_out;
  u16* h    = (u16*)(ob);                    // 25,165,824 B
  u16* wcat = (u16*)(ob + 25165824);         //  9,437,184  [w_proj ; w_gate] (6144 x 768)
  u16* wob  = (u16*)(ob + 34603008);         //  4,718,592
  u16* wkb  = (u16*)(ob + 39321600);         //  1,179,648
  u16* wvb  = (u16*)(ob + 40501248);         //  1,179,648
  u16* wTb  = (u16*)(ob + 41680896);         //     55,296  (total 41.7MB < 50.3MB)

  char* ws = (char*)d_ws;
  u16* valp  = (u16*)(ws);                   // 100,663,296  [dead after conv]
  u16* gateb = (u16*)(ws + 100663296);       // 100,663,296  silu(gate)->gated [dead after out GEMM]
  u16* outb  = (u16*)(ws);                   //  25,165,824  (valp region, valp dead)
  u16* Kbf   = (u16*)(ws + 25165824);        //  25,165,824
  u16* Vbf   = (u16*)(ws + 50331648);        //  25,165,824
  u16* Kt    = (u16*)(ws + 100663296);       //  25,165,824  (gateb region, gateb dead)
  u16* Vt    = (u16*)(ws + 125829120);       //  25,165,824
  u16* Wt    = (u16*)(ws + 150994944);       //  18,874,368  (max used 169.9MB)

  // weight preprocessing
  k_f32_to_bf16<<<2304, 256, 0, stream>>>(w_proj, wcat,           589824);
  k_f32_to_bf16<<<2304, 256, 0, stream>>>(w_gate, wcat + 2359296, 589824);
  k_f32_to_bf16<<<2304, 256, 0, stream>>>(w_out,  wob, 589824);
  k_f32_to_bf16<<<576,  256, 0, stream>>>(w_k,    wkb, 147456);
  k_f32_to_bf16<<<576,  256, 0, stream>>>(w_v,    wvb, 147456);
  k_convw_t<<<12, 256, 0, stream>>>(conv_w, wTb);

  // h = rmsnorm(x) in bf16
  k_rmsnorm<<<4096, 256, 0, stream>>>(x, norm_w, h);

  // [val_pre | silu(gate_pre)] = h @ [w_proj;w_gate]^T  (M=16384, N=6144, K=768)
  k_g8<5><<<1536, 512, 0, stream>>>(h, wcat, valp, gateb, nullptr, nullptr,
                                    3072, 768, 12, 24, 0, 0, 0, 0, 0);
  // gated = silu(conv(val_pre)+b) * siluGate   (in-place into gateb)
  k_conv_gate<<<8192, 384, 0, stream>>>(valp, gateb, wTb, conv_b);

  // out = gated @ w_out^T  (M=16384, N=768, K=3072)
  k_g8<0><<<192, 512, 0, stream>>>(gateb, wob, outb, nullptr, nullptr, nullptr,
                                   768, 3072, 48, 3, 0, 0, 0, 0, 0);
  // K = h @ w_k^T ; V = out @ w_v^T  (M=16384, N=768, K=768)
  k_g8<0><<<192, 512, 0, stream>>>(h, wkb, Kbf, nullptr, nullptr, nullptr,
                                   768, 768, 12, 3, 0, 0, 0, 0, 0);
  k_g8<0><<<192, 512, 0, stream>>>(outb, wvb, Vbf, nullptr, nullptr, nullptr,
                                   768, 768, 12, 3, 0, 0, 0, 0, 0);
  // K^T, V^T per batch: [B, D, T]
  k_transpose<<<dim3(12, 16, 16), 256, 0, stream>>>(Kbf, Kt);
  k_transpose<<<dim3(12, 16, 16), 256, 0, stream>>>(Vbf, Vt);

  // Wt[b][e][d] = (alpha/T) * sum_t V[t,e] K[t,d]  (per-batch 768x768, K=1024)
  k_g8<2><<<dim3(9, 1, 16), 512, 0, stream>>>(Vt, Kt, Wt, nullptr, nullptr, lalpha,
                                              768, 1024, 16, 3,
                                              (long)NDM * NTT, (long)NDM * NTT,
                                              (long)NDM * NDM, 0, 0);
  // final: d_out = x + out + sum_d K[t,d] * Wt[e,d]  (M=16384, N=768, K=768, B per batch)
  k_g8<3><<<192, 512, 0, stream>>>(Kbf, Wt, d_out, outb, x, nullptr,
                                   768, 768, 12, 3, 0, 0, 0,
                                   NTT, (long)NDM * NDM);
}